// Round 2
// baseline (48221.280 us; speedup 1.0000x reference)
//
#include <hip/hip_runtime.h>
#include <hip/hip_bf16.h>

// RecurrentQNet: B=64, S=1024, D=64, H=512, A=16
// Outputs (flat concat): q[64,1024,16], cb_preds[64,1024,64], hidden[1,64,512], ca1_out[64,1024,512]
// Strategy (round 1): fp32 multi-launch baseline.
//   R1 fix: k_gru_step weight staging used `if (tid < 384)` with a 256-thread
//   block -> n-gate weights (g=2) never loaded (uninit/stale LDS). Now a
//   strided loop. Everything else unchanged.

#define B_ 64
#define S_ 1024
#define D_ 64
#define H_ 512
#define A_ 16

// ---------------- K1: GRU gate step ----------------
// grid 128 WGs x 256 thr; WG w handles h-cols j0=w*4..w*4+3, all 64 batches.
// thread tid: b = tid>>2, jj = tid&3.
__global__ __launch_bounds__(256) void k_gru_step(
    int t,
    const float* __restrict__ x,     // [64,1024,64]
    const float* __restrict__ W_ih,  // [1536,128]
    const float* __restrict__ W_hh,  // [1536,512]
    const float* __restrict__ b_ih,  // [1536]
    const float* __restrict__ b_hh,  // [1536]
    const float* __restrict__ pred_ws, // [64,64] (pred_{t-1})
    float* __restrict__ hist,        // h history = ca1 slot, [64,1024,512]
    float* __restrict__ hidden)      // [64,512]
{
    __shared__ __align__(16) float s_in[64 * 132];
    __shared__ __align__(16) float s_w[3 * 4 * 132];

    const int tid = threadIdx.x;
    const int b = tid >> 2;
    const int jj = tid & 3;
    const int j0 = blockIdx.x * 4;
    const int j = j0 + jj;

    float gi0 = 0.f, gi1 = 0.f, gi2 = 0.f;
    float gh0 = 0.f, gh1 = 0.f, gh2 = 0.f;

    // ---- chunk 0: inp = [x_t | pred_{t-1}], K=128, weights = W_ih ----
    for (int i = tid; i < 1024; i += 256) {               // x_t: 64 rows x 16 f4
        int bb = i >> 4, f = i & 15;
        float4 v = *(const float4*)(x + ((size_t)bb * S_ + t) * D_ + f * 4);
        *(float4*)(s_in + bb * 132 + f * 4) = v;
    }
    for (int i = tid; i < 1024; i += 256) {               // pred: 64 rows x 16 f4
        int bb = i >> 4, f = i & 15;
        float4 v;
        if (t > 0) v = *(const float4*)(pred_ws + bb * 64 + f * 4);
        else       v = make_float4(0.f, 0.f, 0.f, 0.f);
        *(float4*)(s_in + bb * 132 + 64 + f * 4) = v;
    }
    // W_ih rows {j0..+3} for each of 3 gates, 128 cols: 384 float4 loads.
    // R1 FIX: must be a strided loop — block has only 256 threads.
    for (int i = tid; i < 384; i += 256) {
        int g = i >> 7, rem = i & 127, wj = rem >> 5, f = rem & 31;
        float4 v = *(const float4*)(W_ih + (size_t)(g * 512 + j0 + wj) * 128 + f * 4);
        *(float4*)(s_w + (g * 4 + wj) * 132 + f * 4) = v;
    }
    __syncthreads();
    {
        const float4* arow = (const float4*)(s_in + b * 132);
        const float4* w0 = (const float4*)(s_w + (0 * 4 + jj) * 132);
        const float4* w1 = (const float4*)(s_w + (1 * 4 + jj) * 132);
        const float4* w2 = (const float4*)(s_w + (2 * 4 + jj) * 132);
#pragma unroll 8
        for (int k4 = 0; k4 < 32; ++k4) {
            float4 a = arow[k4];
            float4 u = w0[k4]; gi0 += a.x * u.x + a.y * u.y + a.z * u.z + a.w * u.w;
            float4 v = w1[k4]; gi1 += a.x * v.x + a.y * v.y + a.z * v.z + a.w * v.w;
            float4 w = w2[k4]; gi2 += a.x * w.x + a.y * w.y + a.z * w.z + a.w * w.w;
        }
    }

    float hprev = 0.f;
    if (t > 0) {
        for (int c = 0; c < 4; ++c) {
            __syncthreads();  // previous chunk consumed
            for (int i = tid; i < 2048; i += 256) {            // h chunk: 64 rows x 32 f4
                int bb = i >> 5, f = i & 31;
                float4 v = *(const float4*)(hist + ((size_t)bb * S_ + (t - 1)) * H_ + c * 128 + f * 4);
                *(float4*)(s_in + bb * 132 + f * 4) = v;
            }
            // W_hh rows {j0..+3} x 3 gates, cols c*128..+127: 384 float4 loads.
            // R1 FIX: strided loop (was `if (tid < 384)`).
            for (int i = tid; i < 384; i += 256) {
                int g = i >> 7, rem = i & 127, wj = rem >> 5, f = rem & 31;
                float4 v = *(const float4*)(W_hh + (size_t)(g * 512 + j0 + wj) * 512 + c * 128 + f * 4);
                *(float4*)(s_w + (g * 4 + wj) * 132 + f * 4) = v;
            }
            __syncthreads();
            const float4* arow = (const float4*)(s_in + b * 132);
            const float4* w0 = (const float4*)(s_w + (0 * 4 + jj) * 132);
            const float4* w1 = (const float4*)(s_w + (1 * 4 + jj) * 132);
            const float4* w2 = (const float4*)(s_w + (2 * 4 + jj) * 132);
#pragma unroll 8
            for (int k4 = 0; k4 < 32; ++k4) {
                float4 a = arow[k4];
                float4 u = w0[k4]; gh0 += a.x * u.x + a.y * u.y + a.z * u.z + a.w * u.w;
                float4 v = w1[k4]; gh1 += a.x * v.x + a.y * v.y + a.z * v.z + a.w * v.w;
                float4 w = w2[k4]; gh2 += a.x * w.x + a.y * w.y + a.z * w.z + a.w * w.w;
            }
        }
        hprev = hist[((size_t)b * S_ + (t - 1)) * H_ + j];
    }

    // gates: PyTorch order (r, z, n); biases added here (correct for t==0 too)
    float r = 1.f / (1.f + __expf(-(gi0 + b_ih[j] + gh0 + b_hh[j])));
    float z = 1.f / (1.f + __expf(-(gi1 + b_ih[512 + j] + gh1 + b_hh[512 + j])));
    float n = tanhf(gi2 + b_ih[1024 + j] + r * (gh2 + b_hh[1024 + j]));
    float hnew = (1.f - z) * n + z * hprev;

    hist[((size_t)b * S_ + t) * H_ + j] = hnew;
    if (t == S_ - 1) hidden[b * H_ + j] = hnew;
}

// ---------------- K2a: u = relu(cb_w1 @ h_t + cb_b1) ----------------
// grid 128 WGs x 256 thr; WG w -> u-cols j0=w*4..+3.
__global__ __launch_bounds__(256) void k_u(
    int t,
    const float* __restrict__ cb_w1, // [512,512]
    const float* __restrict__ cb_b1, // [512]
    const float* __restrict__ hist,  // [64,1024,512]
    float* __restrict__ u_ws)        // [64,512]
{
    __shared__ __align__(16) float s_in[64 * 132];
    __shared__ __align__(16) float s_w[4 * 132];
    const int tid = threadIdx.x;
    const int b = tid >> 2;
    const int jj = tid & 3;
    const int j0 = blockIdx.x * 4;
    const int j = j0 + jj;

    float acc = 0.f;
    for (int c = 0; c < 4; ++c) {
        if (c) __syncthreads();
        for (int i = tid; i < 2048; i += 256) {
            int bb = i >> 5, f = i & 31;
            float4 v = *(const float4*)(hist + ((size_t)bb * S_ + t) * H_ + c * 128 + f * 4);
            *(float4*)(s_in + bb * 132 + f * 4) = v;
        }
        if (tid < 128) {
            int wj = tid >> 5, f = tid & 31;
            float4 v = *(const float4*)(cb_w1 + (size_t)(j0 + wj) * 512 + c * 128 + f * 4);
            *(float4*)(s_w + wj * 132 + f * 4) = v;
        }
        __syncthreads();
        const float4* arow = (const float4*)(s_in + b * 132);
        const float4* wr = (const float4*)(s_w + jj * 132);
#pragma unroll 8
        for (int k4 = 0; k4 < 32; ++k4) {
            float4 a = arow[k4];
            float4 w = wr[k4];
            acc += a.x * w.x + a.y * w.y + a.z * w.z + a.w * w.w;
        }
    }
    acc += cb_b1[j];
    u_ws[b * H_ + j] = fmaxf(acc, 0.f);
}

// ---------------- K2b: pred = cb_w2 @ u + cb_b2 ----------------
// grid 16 WGs x 256 thr; WG w -> d-cols d0=w*4..+3.
__global__ __launch_bounds__(256) void k_pred(
    int t,
    const float* __restrict__ cb_w2, // [64,512]
    const float* __restrict__ cb_b2, // [64]
    const float* __restrict__ u_ws,  // [64,512]
    float* __restrict__ pred_ws,     // [64,64]
    float* __restrict__ cb_preds)    // [64,1024,64]
{
    __shared__ __align__(16) float s_in[64 * 132];
    __shared__ __align__(16) float s_w[4 * 132];
    const int tid = threadIdx.x;
    const int b = tid >> 2;
    const int jj = tid & 3;
    const int d0 = blockIdx.x * 4;
    const int d = d0 + jj;

    float acc = 0.f;
    for (int c = 0; c < 4; ++c) {
        if (c) __syncthreads();
        for (int i = tid; i < 2048; i += 256) {
            int bb = i >> 5, f = i & 31;
            float4 v = *(const float4*)(u_ws + (size_t)bb * H_ + c * 128 + f * 4);
            *(float4*)(s_in + bb * 132 + f * 4) = v;
        }
        if (tid < 128) {
            int wj = tid >> 5, f = tid & 31;
            float4 v = *(const float4*)(cb_w2 + (size_t)(d0 + wj) * 512 + c * 128 + f * 4);
            *(float4*)(s_w + wj * 132 + f * 4) = v;
        }
        __syncthreads();
        const float4* arow = (const float4*)(s_in + b * 132);
        const float4* wr = (const float4*)(s_w + jj * 132);
#pragma unroll 8
        for (int k4 = 0; k4 < 32; ++k4) {
            float4 a = arow[k4];
            float4 w = wr[k4];
            acc += a.x * w.x + a.y * w.y + a.z * w.z + a.w * w.w;
        }
    }
    acc += cb_b2[d];
    pred_ws[b * 64 + d] = acc;
    cb_preds[((size_t)b * S_ + t) * D_ + d] = acc;
}

// ---------------- E1: ca1 = relu(h @ fc_w.T + fc_b), IN PLACE ----------------
// grid 4096 WGs x 256 thr; WG handles 16 full rows (self-contained: loads its
// 16 rows of h fully into LDS, then overwrites them with ca1). No cross-WG hazard.
__global__ __launch_bounds__(256) void k_fc_inplace(
    float* __restrict__ hist,        // in: h rows, out: ca1 rows  [65536,512]
    const float* __restrict__ fc_w,  // [512,512]
    const float* __restrict__ fc_b)  // [512]
{
    __shared__ __align__(16) float s_a[16 * 516];
    const int tid = threadIdx.x;
    const int r = tid & 15;          // row within tile
    const int jset = tid >> 4;       // 0..15
    const int row0 = blockIdx.x * 16;

    for (int i = tid; i < 2048; i += 256) {   // 16 rows x 32 f4
        int rr = i >> 7, f = i & 127;
        float4 v = *(const float4*)(hist + (size_t)(row0 + rr) * H_ + f * 4);
        *(float4*)(s_a + rr * 516 + f * 4) = v;
    }
    __syncthreads();

    float acc[32];
#pragma unroll
    for (int jj = 0; jj < 32; ++jj) acc[jj] = 0.f;

    const float4* arow = (const float4*)(s_a + r * 516);
    for (int k4 = 0; k4 < 128; ++k4) {
        float4 a = arow[k4];
#pragma unroll
        for (int jj = 0; jj < 32; ++jj) {
            int j = jset + (jj << 4);
            float4 w = *(const float4*)(fc_w + (size_t)j * 512 + k4 * 4);
            acc[jj] += a.x * w.x + a.y * w.y + a.z * w.z + a.w * w.w;
        }
    }

    float* crow = hist + (size_t)(row0 + r) * H_;
#pragma unroll
    for (int jj = 0; jj < 32; ++jj) {
        int j = jset + (jj << 4);
        float v = acc[jj] + fc_b[j];
        crow[j] = fmaxf(v, 0.f);
    }
}

// ---------------- E3: q = ca1 @ out_w.T + out_b ----------------
// grid 4096 WGs x 256 thr; WG handles 16 rows x all 16 A-cols.
__global__ __launch_bounds__(256) void k_q(
    const float* __restrict__ ca1,   // [65536,512]
    const float* __restrict__ out_w, // [16,512]
    const float* __restrict__ out_b, // [16]
    float* __restrict__ q)           // [65536,16]
{
    __shared__ __align__(16) float s_a[16 * 516];
    __shared__ __align__(16) float s_w[16 * 516];
    const int tid = threadIdx.x;
    const int r = tid >> 4;          // 0..15 row
    const int a_ = tid & 15;         // 0..15 action
    const int row0 = blockIdx.x * 16;

    for (int i = tid; i < 2048; i += 256) {
        int rr = i >> 7, f = i & 127;
        float4 v = *(const float4*)(ca1 + (size_t)(row0 + rr) * H_ + f * 4);
        *(float4*)(s_a + rr * 516 + f * 4) = v;
    }
    for (int i = tid; i < 2048; i += 256) {
        int rr = i >> 7, f = i & 127;
        float4 v = *(const float4*)(out_w + (size_t)rr * 512 + f * 4);
        *(float4*)(s_w + rr * 516 + f * 4) = v;
    }
    __syncthreads();

    const float4* arow = (const float4*)(s_a + r * 516);
    const float4* wrow = (const float4*)(s_w + a_ * 516);
    float acc = 0.f;
#pragma unroll 8
    for (int k4 = 0; k4 < 128; ++k4) {
        float4 a = arow[k4];
        float4 w = wrow[k4];
        acc += a.x * w.x + a.y * w.y + a.z * w.z + a.w * w.w;
    }
    q[(size_t)(row0 + r) * A_ + a_] = acc + out_b[a_];
}

// ---------------- host ----------------
extern "C" void kernel_launch(void* const* d_in, const int* in_sizes, int n_in,
                              void* d_out, int out_size, void* d_ws, size_t ws_size,
                              hipStream_t stream) {
    const float* x     = (const float*)d_in[0];
    const float* W_ih  = (const float*)d_in[1];
    const float* W_hh  = (const float*)d_in[2];
    const float* b_ih  = (const float*)d_in[3];
    const float* b_hh  = (const float*)d_in[4];
    const float* fc_w  = (const float*)d_in[5];
    const float* fc_b  = (const float*)d_in[6];
    const float* out_w = (const float*)d_in[7];
    const float* out_b = (const float*)d_in[8];
    const float* cb_w1 = (const float*)d_in[9];
    const float* cb_b1 = (const float*)d_in[10];
    const float* cb_w2 = (const float*)d_in[11];
    const float* cb_b2 = (const float*)d_in[12];

    float* q_out  = (float*)d_out;                     // [64,1024,16]
    float* cbp    = q_out + (size_t)B_ * S_ * A_;      // [64,1024,64]
    float* hidden = cbp + (size_t)B_ * S_ * D_;        // [1,64,512]
    float* ca1    = hidden + (size_t)B_ * H_;          // [64,1024,512] (h-history then ca1)

    float* pred_ws = (float*)d_ws;                     // [64,64]
    float* u_ws    = pred_ws + 64 * 64;                // [64,512]

    for (int t = 0; t < S_; ++t) {
        k_gru_step<<<128, 256, 0, stream>>>(t, x, W_ih, W_hh, b_ih, b_hh,
                                            pred_ws, ca1, hidden);
        k_u<<<128, 256, 0, stream>>>(t, cb_w1, cb_b1, ca1, u_ws);
        k_pred<<<16, 256, 0, stream>>>(t, cb_w2, cb_b2, u_ws, pred_ws, cbp);
    }
    k_fc_inplace<<<4096, 256, 0, stream>>>(ca1, fc_w, fc_b);
    k_q<<<4096, 256, 0, stream>>>(ca1, out_w, out_b, q_out);
}